// Round 10
// baseline (196.538 us; speedup 1.0000x reference)
//
#include <hip/hip_runtime.h>
#include <math.h>

// Problem constants (fixed by setup_inputs)
#define B_    2
#define L_    4096
#define H_    8
#define D_    64
#define S_    45      // sample_k
#define NT_   45      // n_top
#define BH_   16      // B*H
#define CHV   64      // cumsum chunk length
#define NCHV  64      // L_/CHV
#define KC    128     // attention key-chunk length
#define NKC   32      // L_/KC
#define SCALE 0.125f  // 1/sqrt(64)
#define NEG_BIG (-1e30f)

// Workspace layout (float element offsets; ints share the same 4B slots).
// VSUM is only live between k1 and k3-scan; CTXP is written in k3-kC, so
// VSUM overlays the start of the CTXP region... but scan and kC now run in
// the SAME dispatch -> VSUM must NOT alias CTXP anymore. Keep them separate.
#define OFF_M     0         // 65536 floats: M[bh][q]
#define OFF_MTOP  65536     // 720 ints:    M_top[bh][u]
#define OFF_MPART 66304     // 23040 floats: m partial [bh][u][kc]
#define OFF_SPART 89344     // 23040 floats: sumexp partial [bh][u][kc]
#define OFF_VSUM  112384    // 65536 floats: vsum[bh][ch][d]
#define OFF_CTXP  177920    // 1474560 floats: ctx partial [bh][kc][u][d]
// total = 177920 + 1474560 = 1652480 floats = 6.6 MB

// DPP row-rotate combine within a 16-lane row (VALU-pipe, no ds_swizzle)
template <int CTRL>
__device__ __forceinline__ float dpp_ror_f(float x) {
    int y = __builtin_amdgcn_update_dpp(0, __float_as_int(x), CTRL, 0xF, 0xF, false);
    return __int_as_float(y);
}

// bf16 <-> f32 bit tricks (bf16 = high 16 bits of fp32; truncation rounding)
__device__ __forceinline__ unsigned short f2bf(float x) {
    return (unsigned short)(__float_as_uint(x) >> 16);
}
__device__ __forceinline__ float bflo(unsigned u) { return __uint_as_float(u << 16); }
__device__ __forceinline__ float bfhi(unsigned u) { return __uint_as_float(u & 0xffff0000u); }

// ---------------------------------------------------------------------------
// k1: FUSED  (a) M scores: blocks < 2048, block = (b, q-octet, hh), wave =
//     TWO q's with interleaved 9-deep gather streams (18 loads in flight;
//     reduce of stream A overlaps fill of stream B). XCD-slab swizzle
//     (blockIdx%8 = XCD; slab (b,hh) = 4MB = one XCD L2). Per sample one
//     coalesced 1KB gather covers 4 heads; dot4 + 4-step DPP row reduce.
//     (b) V chunk sums: blocks >= 2048 (256 blocks x 4 waves).
// ---------------------------------------------------------------------------
__global__ __launch_bounds__(256) void k1(const float* __restrict__ Q,
                                          const float* __restrict__ Kt,
                                          const float* __restrict__ V,
                                          const int* __restrict__ samp,
                                          float* __restrict__ ws)
{
    int tid  = threadIdx.x;
    int w    = tid >> 6;          // 0..3
    int lane = tid & 63;

    if (blockIdx.x < 2048) {
        int i   = blockIdx.x;
        int xcd = i & 7;
        int b   = xcd >> 2;
        int hh  = (xcd >> 1) & 1;
        int qg  = ((i >> 3) << 1) | (xcd & 1);   // q-octet index 0..511

        __shared__ int soff[8 * S_];             // byte offsets idx*2048
        // samp rows for q = qg*8 .. qg*8+7 are contiguous: 360 ints
        for (int e = tid; e < 8 * S_; e += 256)
            soff[e] = samp[qg * (8 * S_) + e] << 11;
        __syncthreads();

        int qa = qg * 8 + w * 2;                 // wave owns qa, qa+1
        int h4 = lane >> 4;

        const float4 qva = *(const float4*)(Q +
            ((((long)b * L_ + qa)     * H_ + hh * 4) << 6) + lane * 4);
        const float4 qvb = *(const float4*)(Q +
            ((((long)b * L_ + qa + 1) * H_ + hh * 4) << 6) + lane * 4);

        const char* kb_base = (const char*)Kt +
            (long)b * L_ * 2048 + hh * 1024 + lane * 16;
        const int* sa = &soff[(w * 2) * S_];
        const int* sb = sa + S_;

        float mxa = NEG_BIG, sma = 0.f, mxb = NEG_BIG, smb = 0.f;
#pragma unroll
        for (int jb = 0; jb < 45; jb += 9) {     // 5 batches x (9+9) gathers
            float4 ka[9], kb[9];
#pragma unroll
            for (int j = 0; j < 9; ++j)
                ka[j] = *(const float4*)(kb_base + sa[jb + j]);
#pragma unroll
            for (int j = 0; j < 9; ++j)
                kb[j] = *(const float4*)(kb_base + sb[jb + j]);
#pragma unroll
            for (int j = 0; j < 9; ++j) {
                float p = qva.x * ka[j].x + qva.y * ka[j].y +
                          qva.z * ka[j].z + qva.w * ka[j].w;
                p += dpp_ror_f<0x121>(p);
                p += dpp_ror_f<0x122>(p);
                p += dpp_ror_f<0x124>(p);
                p += dpp_ror_f<0x128>(p);        // 16-lane row sum
                mxa = fmaxf(mxa, p);
                sma += p;
            }
#pragma unroll
            for (int j = 0; j < 9; ++j) {
                float p = qvb.x * kb[j].x + qvb.y * kb[j].y +
                          qvb.z * kb[j].z + qvb.w * kb[j].w;
                p += dpp_ror_f<0x121>(p);
                p += dpp_ror_f<0x122>(p);
                p += dpp_ror_f<0x124>(p);
                p += dpp_ror_f<0x128>(p);
                mxb = fmaxf(mxb, p);
                smb += p;
            }
        }
        if ((lane & 15) == 0) {
            long base = (long)(b * 8 + hh * 4 + h4) * L_;
            ws[OFF_M + base + qa]     = mxa - sma * (1.0f / (float)L_);
            ws[OFF_M + base + qa + 1] = mxb - smb * (1.0f / (float)L_);
        }
    } else {
        // V chunk sums: wave per (bh, ch), 16 loads in flight
        int unit = (blockIdx.x - 2048) * 4 + w;   // 0..1023
        int bh = unit >> 6, ch = unit & 63;
        int b = bh >> 3, h = bh & 7;
        const float* vp = V + ((((long)b * L_ + (long)ch * CHV) * H_ + h) << 6) + lane;
        float ssum = 0.f;
#pragma unroll
        for (int ib = 0; ib < CHV; ib += 16) {
            float vb[16];
#pragma unroll
            for (int j = 0; j < 16; ++j) vb[j] = vp[(long)(ib + j) * (H_ * D_)];
#pragma unroll
            for (int j = 0; j < 16; ++j) ssum += vb[j];
        }
        ws[OFF_VSUM + unit * 64 + lane] = ssum;
    }
}

// ---------------------------------------------------------------------------
// k2: top-45 per (b,h), 16 blocks. Each of 4 waves: barrier-free iterative
// argmax over its 1024-element quarter (lane-major order -> ballot lowest
// lane = lowest index), sorted 45-list in LDS; then 4-lane shfl merge
// (g-ascending tie-break = lowest global index).
// ---------------------------------------------------------------------------
__global__ __launch_bounds__(256) void k2(float* __restrict__ ws)
{
    int tid  = threadIdx.x;
    int w    = tid >> 6;
    int lane = tid & 63;

    int bh = blockIdx.x;
    int* Mtop = (int*)ws + OFF_MTOP + bh * NT_;

    __shared__ float lv_[4][NT_];
    __shared__ int   li_[4][NT_];

    const float4* m4 = (const float4*)(ws + OFF_M + (long)bh * L_ +
                                       w * 1024 + lane * 16);
    float vals[16];
    {
        float4 a = m4[0], bq = m4[1], c = m4[2], d = m4[3];
        vals[0]=a.x; vals[1]=a.y; vals[2]=a.z; vals[3]=a.w;
        vals[4]=bq.x; vals[5]=bq.y; vals[6]=bq.z; vals[7]=bq.w;
        vals[8]=c.x; vals[9]=c.y; vals[10]=c.z; vals[11]=c.w;
        vals[12]=d.x; vals[13]=d.y; vals[14]=d.z; vals[15]=d.w;
    }
    float lv = NEG_BIG; int li = lane * 16;
#pragma unroll
    for (int j = 0; j < 16; ++j)
        if (vals[j] > lv) { lv = vals[j]; li = lane * 16 + j; }

    for (int r = 0; r < NT_; ++r) {
        float rm = lv;
        rm = fmaxf(rm, dpp_ror_f<0x121>(rm));
        rm = fmaxf(rm, dpp_ror_f<0x122>(rm));
        rm = fmaxf(rm, dpp_ror_f<0x124>(rm));
        rm = fmaxf(rm, dpp_ror_f<0x128>(rm));
        rm = fmaxf(rm, __shfl_xor(rm, 16));
        rm = fmaxf(rm, __shfl_xor(rm, 32));      // wave max in all lanes
        unsigned long long bm = __ballot(lv == rm);
        int winner = __ffsll(bm) - 1;            // lowest lane = lowest idx
        int wi = __shfl(li, winner);
        if (lane == 0) { lv_[w][r] = rm; li_[w][r] = w * 1024 + wi; }
        if (lane == winner) {
#pragma unroll
            for (int j = 0; j < 16; ++j)
                if (j == (wi & 15)) vals[j] = NEG_BIG;
            lv = NEG_BIG; li = lane * 16;
#pragma unroll
            for (int j = 0; j < 16; ++j)
                if (vals[j] > lv) { lv = vals[j]; li = lane * 16 + j; }
        }
    }
    __syncthreads();

    if (w == 0) {
        int g = lane & 3;
        int p = 0;
        float hv = lv_[g][0]; int hi = li_[g][0];
        for (int r = 0; r < NT_; ++r) {
            float v0 = __shfl(hv, 0), v1 = __shfl(hv, 1),
                  v2 = __shfl(hv, 2), v3 = __shfl(hv, 3);
            int   i0 = __shfl(hi, 0), i1 = __shfl(hi, 1),
                  i2 = __shfl(hi, 2), i3 = __shfl(hi, 3);
            float bv = v0; int bi = i0, bg = 0;
            if (v1 > bv) { bv = v1; bi = i1; bg = 1; }
            if (v2 > bv) { bv = v2; bi = i2; bg = 2; }
            if (v3 > bv) { bv = v3; bi = i3; bg = 3; }
            if (lane == 0) Mtop[r] = bi;
            if (g == bg) {
                ++p;
                hv = (p < NT_) ? lv_[g][p] : NEG_BIG;
                hi = (p < NT_) ? li_[g][p] : 0;
            }
        }
    }
}

// ---------------------------------------------------------------------------
// k3: FUSED  (a) attention partials: blocks < 1024 = (bh, kc, ug), ~23
//     selected queries vs one 128-key chunk. K + P in LDS as BF16 (24.4 KB).
//     (b) cumsum write: blocks >= 1024 (256 blocks x 4 waves) — depends only
//     on k1's VSUM, so it OVERLAPS the attention blocks in this dispatch
//     (same-stream kernels serialize; same-dispatch blocks don't).
// ---------------------------------------------------------------------------
#define KPAD16 72   // bf16 row stride: 144B, 16B-aligned
#define NUH    23
__global__ __launch_bounds__(256) void k3(const float* __restrict__ Q,
                                          const float* __restrict__ Kt,
                                          const float* __restrict__ V,
                                          float* __restrict__ out,
                                          float* __restrict__ ws)
{
    __shared__ unsigned short Klds16[KC * KPAD16];  // 18432 B
    __shared__ unsigned short P16[NUH * KC];        // 5888 B
    __shared__ int qpos[NUH];

    int tid = threadIdx.x;

    if (blockIdx.x >= 1024) {
        // ---- cumsum write: wave per (bh, ch); prefix from vsum chunk sums
        int w = tid >> 6, d = tid & 63;
        int unit = (blockIdx.x - 1024) * 4 + w;  // 0..1023
        int bh = unit >> 6, ch = unit & 63;
        int b = bh >> 3, h = bh & 7;

        float acc = 0.f;
        {
            const float* vs = ws + OFF_VSUM + (long)bh * NCHV * 64 + d;
            int c = 0;
            for (; c + 8 <= ch; c += 8) {
                float vb[8];
#pragma unroll
                for (int j = 0; j < 8; ++j) vb[j] = vs[(c + j) * 64];
#pragma unroll
                for (int j = 0; j < 8; ++j) acc += vb[j];
            }
            for (; c < ch; ++c) acc += vs[c * 64];
        }

        const float* vp = V   + ((((long)b * L_ + (long)ch * CHV) * H_ + h) << 6) + d;
        float*       op = out + ((((long)b * L_ + (long)ch * CHV) * H_ + h) << 6) + d;
#pragma unroll
        for (int ib = 0; ib < CHV; ib += 16) {
            float vb[16];
#pragma unroll
            for (int j = 0; j < 16; ++j) vb[j] = vp[(long)(ib + j) * (H_ * D_)];
#pragma unroll
            for (int j = 0; j < 16; ++j) {
                acc += vb[j];
                op[(long)(ib + j) * (H_ * D_)] = acc;
            }
        }
        return;
    }

    // ---- attention partials
    int bh = blockIdx.x >> 6;
    int kc = (blockIdx.x >> 1) & 31;
    int ug = blockIdx.x & 1;
    int b = bh >> 3, h = bh & 7;
    int kbase = kc * KC;
    int u0 = ug * 23;
    int NU = ug ? 22 : 23;

    if (tid < NU) qpos[tid] = ((const int*)ws)[OFF_MTOP + bh * NT_ + tid + u0];

    {
        const float4* ksrc4 = (const float4*)(Kt + ((((long)b * L_ + kbase) * H_ + h) << 6));
#pragma unroll
        for (int i = 0; i < 8; ++i) {
            int e = i * 256 + tid;
            int r = e >> 4, c4 = e & 15;
            float4 kv = ksrc4[(long)r * (H_ * D_ / 4) + c4];
            uint2 pk;
            pk.x = (__float_as_uint(kv.x) >> 16) | (__float_as_uint(kv.y) & 0xffff0000u);
            pk.y = (__float_as_uint(kv.z) >> 16) | (__float_as_uint(kv.w) & 0xffff0000u);
            *(uint2*)&Klds16[r * KPAD16 + c4 * 4] = pk;
        }
    }
    __syncthreads();

    int k = tid & 127, uh = tid >> 7;
    int kpos = kbase + k;
    {
        float kf[64];
#pragma unroll
        for (int j = 0; j < 8; ++j) {
            uint4 U = *(const uint4*)&Klds16[k * KPAD16 + j * 8];
            kf[j*8+0] = bflo(U.x); kf[j*8+1] = bfhi(U.x);
            kf[j*8+2] = bflo(U.y); kf[j*8+3] = bfhi(U.y);
            kf[j*8+4] = bflo(U.z); kf[j*8+5] = bfhi(U.z);
            kf[j*8+6] = bflo(U.w); kf[j*8+7] = bfhi(U.w);
        }

#pragma unroll 3
        for (int j = 0; j < 12; ++j) {
            int ul = uh * 12 + j;
            if (ul > NU - 1) ul = NU - 1;          // clamp (dup write, same val)
            int qp_ = __builtin_amdgcn_readfirstlane(qpos[ul]);
            const float4* qrow = (const float4*)(Q + ((((long)b * L_ + qp_) * H_ + h) << 6));
            float a0 = 0.f, a1 = 0.f, a2 = 0.f, a3 = 0.f;
#pragma unroll
            for (int jj = 0; jj < 16; jj += 4) {
                float4 q0 = qrow[jj + 0], q1 = qrow[jj + 1];
                float4 q2 = qrow[jj + 2], q3 = qrow[jj + 3];
                a0 += q0.x * kf[jj*4+ 0] + q0.y * kf[jj*4+ 1] +
                      q0.z * kf[jj*4+ 2] + q0.w * kf[jj*4+ 3];
                a1 += q1.x * kf[jj*4+ 4] + q1.y * kf[jj*4+ 5] +
                      q1.z * kf[jj*4+ 6] + q1.w * kf[jj*4+ 7];
                a2 += q2.x * kf[jj*4+ 8] + q2.y * kf[jj*4+ 9] +
                      q2.z * kf[jj*4+10] + q2.w * kf[jj*4+11];
                a3 += q3.x * kf[jj*4+12] + q3.y * kf[jj*4+13] +
                      q3.z * kf[jj*4+14] + q3.w * kf[jj*4+15];
            }
            float sc = ((a0 + a1) + (a2 + a3)) * SCALE;
            if (kpos > qp_) sc = NEG_BIG;   // causal mask
            P16[ul * KC + k] = f2bf(sc);
        }
    }
    __syncthreads();

    int lane = tid & 63, w = tid >> 6;
    for (int ul = w; ul < NU; ul += 4) {
        float s0 = bflo(P16[ul * KC + lane]);
        float s1 = bflo(P16[ul * KC + 64 + lane]);
        float m = fmaxf(s0, s1);
#pragma unroll
        for (int off = 32; off; off >>= 1) m = fmaxf(m, __shfl_xor(m, off));
        float e0 = __expf(s0 - m), e1 = __expf(s1 - m);
        unsigned short b0 = f2bf(e0), b1 = f2bf(e1);
        P16[ul * KC + lane]      = b0;
        P16[ul * KC + 64 + lane] = b1;
        float sm = bflo(b0) + bflo(b1);
#pragma unroll
        for (int off = 32; off; off >>= 1) sm += __shfl_xor(sm, off);
        if (lane == 0) {
            ws[OFF_MPART + ((long)bh * NT_ + u0 + ul) * NKC + kc] = m;
            ws[OFF_SPART + ((long)bh * NT_ + u0 + ul) * NKC + kc] = sm;
        }
    }
    __syncthreads();

    {
        const float* vsrc = V + ((((long)b * L_ + kbase) * H_ + h) << 6);
        float ctx[6];
#pragma unroll
        for (int j = 0; j < 6; ++j) ctx[j] = 0.f;
        for (int kk8 = 0; kk8 < 16; ++kk8) {
            float v[8];
#pragma unroll
            for (int t = 0; t < 8; ++t)
                v[t] = vsrc[(long)(kk8 * 8 + t) * (H_ * D_) + lane];
#pragma unroll
            for (int j = 0; j < 6; ++j) {
                int ul = w + j * 4;
                if (ul < NU) {
                    uint4 U = *(const uint4*)&P16[ul * KC + kk8 * 8];
                    ctx[j] += bflo(U.x) * v[0] + bfhi(U.x) * v[1]
                            + bflo(U.y) * v[2] + bfhi(U.y) * v[3]
                            + bflo(U.z) * v[4] + bfhi(U.z) * v[5]
                            + bflo(U.w) * v[6] + bfhi(U.w) * v[7];
                }
            }
        }
#pragma unroll
        for (int j = 0; j < 6; ++j) {
            int ul = w + j * 4;
            if (ul < NU)
                ws[OFF_CTXP + ((long)(bh * NKC + kc) * NT_ + u0 + ul) * 64 + lane] = ctx[j];
        }
    }
}

// ---------------------------------------------------------------------------
// kD: merge chunk partials (log-sum-exp) and overwrite selected rows.
// One 64-thread block per (bh,u) unit: 720 blocks.
// ---------------------------------------------------------------------------
__global__ __launch_bounds__(64) void kD(float* __restrict__ out,
                                         const float* __restrict__ ws)
{
    int lane = threadIdx.x;
    int unit = blockIdx.x;
    int bh = unit / NT_, u = unit - bh * NT_;
    int b = bh >> 3, h = bh & 7;

    const float4* mp4 = (const float4*)(ws + OFF_MPART + ((long)bh * NT_ + u) * NKC);
    const float4* sp4 = (const float4*)(ws + OFF_SPART + ((long)bh * NT_ + u) * NKC);

    float mc[NKC], sc[NKC];
    float m = NEG_BIG;
#pragma unroll
    for (int c4 = 0; c4 < NKC / 4; ++c4) {
        float4 mv = mp4[c4];
        float4 sv = sp4[c4];
        mc[c4 * 4 + 0] = mv.x; mc[c4 * 4 + 1] = mv.y;
        mc[c4 * 4 + 2] = mv.z; mc[c4 * 4 + 3] = mv.w;
        sc[c4 * 4 + 0] = sv.x; sc[c4 * 4 + 1] = sv.y;
        sc[c4 * 4 + 2] = sv.z; sc[c4 * 4 + 3] = sv.w;
        m = fmaxf(m, fmaxf(fmaxf(mv.x, mv.y), fmaxf(mv.z, mv.w)));
    }
    float T = 0.f, ctx = 0.f;
#pragma unroll
    for (int c = 0; c < NKC; ++c) {
        float wgt = __expf(mc[c] - m);
        T   += sc[c] * wgt;
        ctx += ws[OFF_CTXP + ((long)(bh * NKC + c) * NT_ + u) * 64 + lane] * wgt;
    }
    int qp = ((const int*)ws)[OFF_MTOP + bh * NT_ + u];
    out[((((long)b * L_ + qp) * H_ + h) << 6) + lane] = ctx / T;
}

// ---------------------------------------------------------------------------
extern "C" void kernel_launch(void* const* d_in, const int* in_sizes, int n_in,
                              void* d_out, int out_size, void* d_ws, size_t ws_size,
                              hipStream_t stream)
{
    const float* Q    = (const float*)d_in[0];
    const float* K    = (const float*)d_in[1];
    const float* V    = (const float*)d_in[2];
    const int*   samp = (const int*)d_in[4];   // d_in[3] = attn_mask (unused)
    float* out = (float*)d_out;
    float* ws  = (float*)d_ws;

    // 1: M scores (2048 blocks, wave = 2 q's) + V chunk sums (256 blocks)
    k1<<<2304, 256, 0, stream>>>(Q, K, V, samp, ws);
    // 2: top-45 (16 blocks)
    k2<<<16, 256, 0, stream>>>(ws);
    // 3: attention partials (1024 blocks) overlapped with cumsum (256 blocks)
    k3<<<1280, 256, 0, stream>>>(Q, K, V, out, ws);
    // 4: merge + scatter selected rows (720 x 64-thread blocks)
    kD<<<720, 64, 0, stream>>>(out, ws);
}

// Round 11
// 189.411 us; speedup vs baseline: 1.0376x; 1.0376x over previous
//
#include <hip/hip_runtime.h>
#include <math.h>

// Problem constants (fixed by setup_inputs)
#define B_    2
#define L_    4096
#define H_    8
#define D_    64
#define S_    45      // sample_k
#define NT_   45      // n_top
#define BH_   16      // B*H
#define CHV   64      // cumsum chunk length
#define NCHV  64      // L_/CHV
#define KC    128     // attention key-chunk length
#define NKC   32      // L_/KC
#define SCALE 0.125f  // 1/sqrt(64)
#define NEG_BIG (-1e30f)

// Workspace layout (float element offsets; ints share the same 4B slots).
// scan and kC run in the SAME dispatch (k3) -> VSUM must not alias CTXP.
#define OFF_M     0         // 65536 floats: M[bh][q]
#define OFF_MTOP  65536     // 720 ints:    M_top[bh][u]
#define OFF_MPART 66304     // 23040 floats: m partial [bh][u][kc]
#define OFF_SPART 89344     // 23040 floats: sumexp partial [bh][u][kc]
#define OFF_VSUM  112384    // 65536 floats: vsum[bh][ch][d]
#define OFF_CTXP  177920    // 1474560 floats: ctx partial [bh][kc][u][d]
// total = 1652480 floats = 6.6 MB

// DPP row-rotate combine within a 16-lane row (VALU-pipe, no ds_swizzle)
template <int CTRL>
__device__ __forceinline__ float dpp_ror_f(float x) {
    int y = __builtin_amdgcn_update_dpp(0, __float_as_int(x), CTRL, 0xF, 0xF, false);
    return __int_as_float(y);
}

// bf16 <-> f32 bit tricks (bf16 = high 16 bits of fp32; truncation rounding)
__device__ __forceinline__ unsigned short f2bf(float x) {
    return (unsigned short)(__float_as_uint(x) >> 16);
}
__device__ __forceinline__ float bflo(unsigned u) { return __uint_as_float(u << 16); }
__device__ __forceinline__ float bfhi(unsigned u) { return __uint_as_float(u & 0xffff0000u); }

// ---------------------------------------------------------------------------
// k1: FUSED  (a) M scores: blocks < 4096, block = (b, q-quad, hh), wave = one
//     q (R9 form: VGPR ~52, occ ~34%, 44 us — R10's 2-q interleave hit VGPR
//     92 / occ 18% and regressed; k1 is TLP-limited, keep registers low).
//     XCD-slab swizzle: blockIdx%8 = XCD; slab (b,hh) = 4MB = one XCD L2.
//     Per sample one coalesced 1KB gather covers 4 heads (lane = 16B chunk);
//     dot4 + 4-step DPP reduce per 16-lane head group.
//     (b) V chunk sums: blocks >= 4096 (256 blocks x 4 waves).
// ---------------------------------------------------------------------------
__global__ __launch_bounds__(256) void k1(const float* __restrict__ Q,
                                          const float* __restrict__ Kt,
                                          const float* __restrict__ V,
                                          const int* __restrict__ samp,
                                          float* __restrict__ ws)
{
    int tid  = threadIdx.x;
    int w    = tid >> 6;          // 0..3
    int lane = tid & 63;

    if (blockIdx.x < 4096) {
        int i   = blockIdx.x;
        int xcd = i & 7;
        int b   = xcd >> 2;
        int hh  = (xcd >> 1) & 1;
        int qq  = ((i >> 3) << 1) | (xcd & 1);   // q-quad index 0..1023

        __shared__ int soff[4][S_];              // byte offsets idx*2048
        if (tid < 4 * S_) {
            int qs = tid / S_, ss = tid - qs * S_;
            soff[qs][ss] = samp[(qq * 4 + qs) * S_ + ss] << 11;
        }
        __syncthreads();

        int q  = qq * 4 + w;                     // wave owns one q
        int h4 = lane >> 4;                      // head within half

        const float4 q4 = *(const float4*)(Q +
            ((((long)b * L_ + q) * H_ + hh * 4) << 6) + lane * 4);

        const char* kb_base = (const char*)Kt +
            (long)b * L_ * 2048 + hh * 1024 + lane * 16;

        float mx = NEG_BIG, sm = 0.f;
#pragma unroll
        for (int jb = 0; jb < 45; jb += 15) {    // 3 batches x 15 gathers
            float4 kb[15];
#pragma unroll
            for (int j = 0; j < 15; ++j)
                kb[j] = *(const float4*)(kb_base + soff[w][jb + j]);
#pragma unroll
            for (int j = 0; j < 15; ++j) {
                float p = q4.x * kb[j].x + q4.y * kb[j].y +
                          q4.z * kb[j].z + q4.w * kb[j].w;
                p += dpp_ror_f<0x121>(p);   // ror 1
                p += dpp_ror_f<0x122>(p);   // ror 2
                p += dpp_ror_f<0x124>(p);   // ror 4
                p += dpp_ror_f<0x128>(p);   // ror 8 -> 16-lane row sum
                mx = fmaxf(mx, p);
                sm += p;
            }
        }
        if ((lane & 15) == 0)
            ws[OFF_M + ((long)(b * 8 + hh * 4 + h4)) * L_ + q] =
                mx - sm * (1.0f / (float)L_);
    } else {
        // V chunk sums: wave per (bh, ch), 16 loads in flight
        int unit = (blockIdx.x - 4096) * 4 + w;   // 0..1023
        int bh = unit >> 6, ch = unit & 63;
        int b = bh >> 3, h = bh & 7;
        const float* vp = V + ((((long)b * L_ + (long)ch * CHV) * H_ + h) << 6) + lane;
        float ssum = 0.f;
#pragma unroll
        for (int ib = 0; ib < CHV; ib += 16) {
            float vb[16];
#pragma unroll
            for (int j = 0; j < 16; ++j) vb[j] = vp[(long)(ib + j) * (H_ * D_)];
#pragma unroll
            for (int j = 0; j < 16; ++j) ssum += vb[j];
        }
        ws[OFF_VSUM + unit * 64 + lane] = ssum;
    }
}

// ---------------------------------------------------------------------------
// k2: top-45 per (b,h), 16 blocks. Each of 4 waves: barrier-free iterative
// argmax over its 1024-element quarter (lane-major order -> ballot lowest
// lane = lowest index), sorted 45-list in LDS; then 4-lane shfl merge
// (g-ascending tie-break = lowest global index).
// ---------------------------------------------------------------------------
__global__ __launch_bounds__(256) void k2(float* __restrict__ ws)
{
    int tid  = threadIdx.x;
    int w    = tid >> 6;
    int lane = tid & 63;

    int bh = blockIdx.x;
    int* Mtop = (int*)ws + OFF_MTOP + bh * NT_;

    __shared__ float lv_[4][NT_];
    __shared__ int   li_[4][NT_];

    const float4* m4 = (const float4*)(ws + OFF_M + (long)bh * L_ +
                                       w * 1024 + lane * 16);
    float vals[16];
    {
        float4 a = m4[0], bq = m4[1], c = m4[2], d = m4[3];
        vals[0]=a.x; vals[1]=a.y; vals[2]=a.z; vals[3]=a.w;
        vals[4]=bq.x; vals[5]=bq.y; vals[6]=bq.z; vals[7]=bq.w;
        vals[8]=c.x; vals[9]=c.y; vals[10]=c.z; vals[11]=c.w;
        vals[12]=d.x; vals[13]=d.y; vals[14]=d.z; vals[15]=d.w;
    }
    float lv = NEG_BIG; int li = lane * 16;
#pragma unroll
    for (int j = 0; j < 16; ++j)
        if (vals[j] > lv) { lv = vals[j]; li = lane * 16 + j; }

    for (int r = 0; r < NT_; ++r) {
        float rm = lv;
        rm = fmaxf(rm, dpp_ror_f<0x121>(rm));
        rm = fmaxf(rm, dpp_ror_f<0x122>(rm));
        rm = fmaxf(rm, dpp_ror_f<0x124>(rm));
        rm = fmaxf(rm, dpp_ror_f<0x128>(rm));
        rm = fmaxf(rm, __shfl_xor(rm, 16));
        rm = fmaxf(rm, __shfl_xor(rm, 32));      // wave max in all lanes
        unsigned long long bm = __ballot(lv == rm);
        int winner = __ffsll(bm) - 1;            // lowest lane = lowest idx
        int wi = __shfl(li, winner);
        if (lane == 0) { lv_[w][r] = rm; li_[w][r] = w * 1024 + wi; }
        if (lane == winner) {
#pragma unroll
            for (int j = 0; j < 16; ++j)
                if (j == (wi & 15)) vals[j] = NEG_BIG;
            lv = NEG_BIG; li = lane * 16;
#pragma unroll
            for (int j = 0; j < 16; ++j)
                if (vals[j] > lv) { lv = vals[j]; li = lane * 16 + j; }
        }
    }
    __syncthreads();

    if (w == 0) {
        int g = lane & 3;
        int p = 0;
        float hv = lv_[g][0]; int hi = li_[g][0];
        for (int r = 0; r < NT_; ++r) {
            float v0 = __shfl(hv, 0), v1 = __shfl(hv, 1),
                  v2 = __shfl(hv, 2), v3 = __shfl(hv, 3);
            int   i0 = __shfl(hi, 0), i1 = __shfl(hi, 1),
                  i2 = __shfl(hi, 2), i3 = __shfl(hi, 3);
            float bv = v0; int bi = i0, bg = 0;
            if (v1 > bv) { bv = v1; bi = i1; bg = 1; }
            if (v2 > bv) { bv = v2; bi = i2; bg = 2; }
            if (v3 > bv) { bv = v3; bi = i3; bg = 3; }
            if (lane == 0) Mtop[r] = bi;
            if (g == bg) {
                ++p;
                hv = (p < NT_) ? lv_[g][p] : NEG_BIG;
                hi = (p < NT_) ? li_[g][p] : 0;
            }
        }
    }
}

// ---------------------------------------------------------------------------
// k3: FUSED  (a) attention partials: blocks < 1024 = (bh, kc, ug).
//     NEW: uniform causal chunk-skip — for (kc,u) with kbase > qp the whole
//     128-key chunk is masked (~50% of pairs): skip the 64-FMA dot + Q loads
//     in QK (write NEG_BIG -> kD weight exactly 0) and skip masked-u MACs +
//     stores in PV (kD multiplies unread CTXP by 0.0; 0xAA poison is finite).
//     (b) cumsum write: blocks >= 1024 — depends only on k1's VSUM, so it
//     overlaps the attention blocks within this dispatch.
// ---------------------------------------------------------------------------
#define KPAD16 72   // bf16 row stride: 144B, 16B-aligned
#define NUH    23
__global__ __launch_bounds__(256) void k3(const float* __restrict__ Q,
                                          const float* __restrict__ Kt,
                                          const float* __restrict__ V,
                                          float* __restrict__ out,
                                          float* __restrict__ ws)
{
    __shared__ unsigned short Klds16[KC * KPAD16];  // 18432 B
    __shared__ unsigned short P16[NUH * KC];        // 5888 B
    __shared__ int qpos[NUH];

    int tid = threadIdx.x;

    if (blockIdx.x >= 1024) {
        // ---- cumsum write: wave per (bh, ch); prefix from vsum chunk sums
        int w = tid >> 6, d = tid & 63;
        int unit = (blockIdx.x - 1024) * 4 + w;  // 0..1023
        int bh = unit >> 6, ch = unit & 63;
        int b = bh >> 3, h = bh & 7;

        float acc = 0.f;
        {
            const float* vs = ws + OFF_VSUM + (long)bh * NCHV * 64 + d;
            int c = 0;
            for (; c + 8 <= ch; c += 8) {
                float vb[8];
#pragma unroll
                for (int j = 0; j < 8; ++j) vb[j] = vs[(c + j) * 64];
#pragma unroll
                for (int j = 0; j < 8; ++j) acc += vb[j];
            }
            for (; c < ch; ++c) acc += vs[c * 64];
        }

        const float* vp = V   + ((((long)b * L_ + (long)ch * CHV) * H_ + h) << 6) + d;
        float*       op = out + ((((long)b * L_ + (long)ch * CHV) * H_ + h) << 6) + d;
#pragma unroll
        for (int ib = 0; ib < CHV; ib += 16) {
            float vb[16];
#pragma unroll
            for (int j = 0; j < 16; ++j) vb[j] = vp[(long)(ib + j) * (H_ * D_)];
#pragma unroll
            for (int j = 0; j < 16; ++j) {
                acc += vb[j];
                op[(long)(ib + j) * (H_ * D_)] = acc;
            }
        }
        return;
    }

    // ---- attention partials
    int bh = blockIdx.x >> 6;
    int kc = (blockIdx.x >> 1) & 31;
    int ug = blockIdx.x & 1;
    int b = bh >> 3, h = bh & 7;
    int kbase = kc * KC;
    int u0 = ug * 23;
    int NU = ug ? 22 : 23;

    if (tid < NU) qpos[tid] = ((const int*)ws)[OFF_MTOP + bh * NT_ + tid + u0];

    {
        const float4* ksrc4 = (const float4*)(Kt + ((((long)b * L_ + kbase) * H_ + h) << 6));
#pragma unroll
        for (int i = 0; i < 8; ++i) {
            int e = i * 256 + tid;
            int r = e >> 4, c4 = e & 15;
            float4 kv = ksrc4[(long)r * (H_ * D_ / 4) + c4];
            uint2 pk;
            pk.x = (__float_as_uint(kv.x) >> 16) | (__float_as_uint(kv.y) & 0xffff0000u);
            pk.y = (__float_as_uint(kv.z) >> 16) | (__float_as_uint(kv.w) & 0xffff0000u);
            *(uint2*)&Klds16[r * KPAD16 + c4 * 4] = pk;
        }
    }
    __syncthreads();

    int k = tid & 127, uh = tid >> 7;
    int kpos = kbase + k;
    {
        float kf[64];
#pragma unroll
        for (int j = 0; j < 8; ++j) {
            uint4 U = *(const uint4*)&Klds16[k * KPAD16 + j * 8];
            kf[j*8+0] = bflo(U.x); kf[j*8+1] = bfhi(U.x);
            kf[j*8+2] = bflo(U.y); kf[j*8+3] = bfhi(U.y);
            kf[j*8+4] = bflo(U.z); kf[j*8+5] = bfhi(U.z);
            kf[j*8+6] = bflo(U.w); kf[j*8+7] = bfhi(U.w);
        }

#pragma unroll 3
        for (int j = 0; j < 12; ++j) {
            int ul = uh * 12 + j;
            if (ul > NU - 1) ul = NU - 1;          // clamp (dup write, same val)
            int qp_ = __builtin_amdgcn_readfirstlane(qpos[ul]);
            if (kbase > qp_) {                     // whole chunk causally masked
                P16[ul * KC + k] = f2bf(NEG_BIG);  // -> kD weight exactly 0
                continue;
            }
            const float4* qrow = (const float4*)(Q + ((((long)b * L_ + qp_) * H_ + h) << 6));
            float a0 = 0.f, a1 = 0.f, a2 = 0.f, a3 = 0.f;
#pragma unroll
            for (int jj = 0; jj < 16; jj += 4) {
                float4 q0 = qrow[jj + 0], q1 = qrow[jj + 1];
                float4 q2 = qrow[jj + 2], q3 = qrow[jj + 3];
                a0 += q0.x * kf[jj*4+ 0] + q0.y * kf[jj*4+ 1] +
                      q0.z * kf[jj*4+ 2] + q0.w * kf[jj*4+ 3];
                a1 += q1.x * kf[jj*4+ 4] + q1.y * kf[jj*4+ 5] +
                      q1.z * kf[jj*4+ 6] + q1.w * kf[jj*4+ 7];
                a2 += q2.x * kf[jj*4+ 8] + q2.y * kf[jj*4+ 9] +
                      q2.z * kf[jj*4+10] + q2.w * kf[jj*4+11];
                a3 += q3.x * kf[jj*4+12] + q3.y * kf[jj*4+13] +
                      q3.z * kf[jj*4+14] + q3.w * kf[jj*4+15];
            }
            float sc = ((a0 + a1) + (a2 + a3)) * SCALE;
            if (kpos > qp_) sc = NEG_BIG;   // partial causal mask
            P16[ul * KC + k] = f2bf(sc);
        }
    }
    __syncthreads();

    int lane = tid & 63, w = tid >> 6;
    for (int ul = w; ul < NU; ul += 4) {
        float s0 = bflo(P16[ul * KC + lane]);
        float s1 = bflo(P16[ul * KC + 64 + lane]);
        float m = fmaxf(s0, s1);
#pragma unroll
        for (int off = 32; off; off >>= 1) m = fmaxf(m, __shfl_xor(m, off));
        float e0 = __expf(s0 - m), e1 = __expf(s1 - m);
        unsigned short b0 = f2bf(e0), b1 = f2bf(e1);
        P16[ul * KC + lane]      = b0;
        P16[ul * KC + 64 + lane] = b1;
        float sm = bflo(b0) + bflo(b1);
#pragma unroll
        for (int off = 32; off; off >>= 1) sm += __shfl_xor(sm, off);
        if (lane == 0) {
            ws[OFF_MPART + ((long)bh * NT_ + u0 + ul) * NKC + kc] = m;
            ws[OFF_SPART + ((long)bh * NT_ + u0 + ul) * NKC + kc] = sm;
        }
    }
    __syncthreads();

    {
        const float* vsrc = V + ((((long)b * L_ + kbase) * H_ + h) << 6);
        // per-u active flags (wave-uniform per j): masked u -> kD wgt = 0,
        // CTXP unread-as-nonzero is fine (multiplied by exactly 0)
        bool act[6];
        int nact = 0;
#pragma unroll
        for (int j = 0; j < 6; ++j) {
            int ul = w + j * 4;
            act[j] = (ul < NU) && (kbase <= qpos[ul]);
            nact += act[j] ? 1 : 0;
        }
        if (nact) {
            float ctx[6];
#pragma unroll
            for (int j = 0; j < 6; ++j) ctx[j] = 0.f;
            for (int kk8 = 0; kk8 < 16; ++kk8) {
                float v[8];
#pragma unroll
                for (int t = 0; t < 8; ++t)
                    v[t] = vsrc[(long)(kk8 * 8 + t) * (H_ * D_) + lane];
#pragma unroll
                for (int j = 0; j < 6; ++j) {
                    if (act[j]) {
                        int ul = w + j * 4;
                        uint4 U = *(const uint4*)&P16[ul * KC + kk8 * 8];
                        ctx[j] += bflo(U.x) * v[0] + bfhi(U.x) * v[1]
                                + bflo(U.y) * v[2] + bfhi(U.y) * v[3]
                                + bflo(U.z) * v[4] + bfhi(U.z) * v[5]
                                + bflo(U.w) * v[6] + bfhi(U.w) * v[7];
                    }
                }
            }
#pragma unroll
            for (int j = 0; j < 6; ++j) {
                int ul = w + j * 4;
                if (act[j])
                    ws[OFF_CTXP + ((long)(bh * NKC + kc) * NT_ + u0 + ul) * 64 + lane] = ctx[j];
            }
        }
    }
}

// ---------------------------------------------------------------------------
// kD: merge chunk partials (log-sum-exp) and overwrite selected rows.
// One 64-thread block per (bh,u) unit: 720 blocks.
// ---------------------------------------------------------------------------
__global__ __launch_bounds__(64) void kD(float* __restrict__ out,
                                         const float* __restrict__ ws)
{
    int lane = threadIdx.x;
    int unit = blockIdx.x;
    int bh = unit / NT_, u = unit - bh * NT_;
    int b = bh >> 3, h = bh & 7;

    const float4* mp4 = (const float4*)(ws + OFF_MPART + ((long)bh * NT_ + u) * NKC);
    const float4* sp4 = (const float4*)(ws + OFF_SPART + ((long)bh * NT_ + u) * NKC);

    float mc[NKC], sc[NKC];
    float m = NEG_BIG;
#pragma unroll
    for (int c4 = 0; c4 < NKC / 4; ++c4) {
        float4 mv = mp4[c4];
        float4 sv = sp4[c4];
        mc[c4 * 4 + 0] = mv.x; mc[c4 * 4 + 1] = mv.y;
        mc[c4 * 4 + 2] = mv.z; mc[c4 * 4 + 3] = mv.w;
        sc[c4 * 4 + 0] = sv.x; sc[c4 * 4 + 1] = sv.y;
        sc[c4 * 4 + 2] = sv.z; sc[c4 * 4 + 3] = sv.w;
        m = fmaxf(m, fmaxf(fmaxf(mv.x, mv.y), fmaxf(mv.z, mv.w)));
    }
    float T = 0.f, ctx = 0.f;
#pragma unroll
    for (int c = 0; c < NKC; ++c) {
        float wgt = __expf(mc[c] - m);   // fully-masked chunks: exactly 0
        T   += sc[c] * wgt;
        ctx += ws[OFF_CTXP + ((long)(bh * NKC + c) * NT_ + u) * 64 + lane] * wgt;
    }
    int qp = ((const int*)ws)[OFF_MTOP + bh * NT_ + u];
    out[((((long)b * L_ + qp) * H_ + h) << 6) + lane] = ctx / T;
}

// ---------------------------------------------------------------------------
extern "C" void kernel_launch(void* const* d_in, const int* in_sizes, int n_in,
                              void* d_out, int out_size, void* d_ws, size_t ws_size,
                              hipStream_t stream)
{
    const float* Q    = (const float*)d_in[0];
    const float* K    = (const float*)d_in[1];
    const float* V    = (const float*)d_in[2];
    const int*   samp = (const int*)d_in[4];   // d_in[3] = attn_mask (unused)
    float* out = (float*)d_out;
    float* ws  = (float*)d_ws;

    // 1: M scores (4096 blocks, wave = one q) + V chunk sums (256 blocks)
    k1<<<4352, 256, 0, stream>>>(Q, K, V, samp, ws);
    // 2: top-45 (16 blocks)
    k2<<<16, 256, 0, stream>>>(ws);
    // 3: attention partials (1024 blocks, causal chunk-skip) + cumsum (256)
    k3<<<1280, 256, 0, stream>>>(Q, K, V, out, ws);
    // 4: merge + scatter selected rows (720 x 64-thread blocks)
    kD<<<720, 64, 0, stream>>>(out, ws);
}